// Round 13
// baseline (285.673 us; speedup 1.0000x reference)
//
#include <hip/hip_runtime.h>

typedef __bf16 bf16x8 __attribute__((ext_vector_type(8)));
typedef float f32x4 __attribute__((ext_vector_type(4)));

#define INV_SQRT3f 0.57735026918962576f

// ---------------- kernel 0: weight prep into MFMA B-fragment layout ----------------
// For each weight W[c][w] (c = contraction, w = out col), place bf16 value at
// fragment slot: block (Wi,kt,ct) of 1KB, lane = (c&31)/8*16 + (w&15), j = c&7.
__global__ void wprep_kernel(const float* __restrict__ wss,
                             const float* __restrict__ wsv,
                             const float* __restrict__ wvs,
                             const float* __restrict__ wvv,
                             unsigned short* __restrict__ wfrag) {
  int tid = blockIdx.x * 256 + threadIdx.x;  // 0..65535
  int Wi = tid >> 14;
  int idx = tid & 16383;
  int c = idx >> 7;
  int w = idx & 127;
  const float* src = (Wi == 0) ? wss : (Wi == 1) ? wsv : (Wi == 2) ? wvs : wvv;
  float v = src[idx];
  if (Wi == 3) v *= INV_SQRT3f;  // fold inv_sqrt3 into w_vv
  unsigned u = __builtin_bit_cast(unsigned, v);
  u += 0x7FFFu + ((u >> 16) & 1u);  // RNE to bf16
  int kt = c >> 5, kk = c & 31, g = kk >> 3, j = kk & 7;
  int ct = w >> 4, n = w & 15;
  wfrag[(((Wi * 4 + kt) * 8 + ct) << 9) + (g * 16 + n) * 8 + j] = (unsigned short)(u >> 16);
}

// compile-time component select (indices constant after full unroll)
__device__ __forceinline__ float fc(const float4& v, int i) {
  return (i == 0) ? v.x : (i == 1) ? v.y : (i == 2) ? v.z : v.w;
}

// One kt-slice of a row's raw x data: 32 floats/lane (8 xs + 24 xv).
struct Chunk {
  float4 fs[2];
  float4 fv[6];
};

__device__ __forceinline__ void load_chunk(Chunk& c, const float* __restrict__ x,
                                           int rowA, int kt, int g) {
  const float* px = x + (size_t)rowA * 512;
#pragma unroll
  for (int q = 0; q < 2; ++q)
    c.fs[q] = *(const float4*)(px + kt * 32 + g * 8 + q * 4);
#pragma unroll
  for (int q = 0; q < 6; ++q)
    c.fv[q] = *(const float4*)(px + 128 + kt * 96 + g * 24 + q * 4);
}

// Fragments for one kt-slice: 6 per kt (yv applied at the OUTPUT in the
// epilogue — row-scaling commutes through the matmul; r10-verified).
struct FragK {
  bf16x8 ss, sv, dd, v0, v1, v2;
};

__device__ __forceinline__ void convert_chunk(FragK& F, const Chunk& c, const float4 yA) {
  const float ys = yA.x, yv0 = yA.y, yv1 = yA.z, yv2 = yA.w;
#pragma unroll
  for (int j = 0; j < 8; ++j) {
    float s = fc(c.fs[j >> 2], j & 3);
    float a = fc(c.fv[(3 * j) >> 2], (3 * j) & 3);
    float bb = fc(c.fv[(3 * j + 1) >> 2], (3 * j + 1) & 3);
    float cc = fc(c.fv[(3 * j + 2) >> 2], (3 * j + 2) & 3);
    F.ss[j] = (__bf16)(ys * s);
    F.sv[j] = (__bf16)(s);
    F.v0[j] = (__bf16)(ys * a);
    F.v1[j] = (__bf16)(ys * bb);
    F.v2[j] = (__bf16)(ys * cc);
    F.dd[j] = (__bf16)fmaf(a, yv0, fmaf(bb, yv1, cc * yv2));
  }
}

// 2-waves/SIMD retry with the LEAN structure.  History: r4/r5 corrupted
// ((512,2) cap forced spill through a ~290-live structure); r9 passed but
// regressed (8-frag ~240-live + temps -> AGPR overflow to scratch under the
// cap).  This version is r10's exact math (6-frag, P/Q epilogue, DISTANCE-1)
// at 8 waves: live set ~210 regs -> fits the 256 cap with headroom, no
// scratch.  8 waves x 1 block/CU = 2 waves/SIMD: the exposed per-ct
// ds_read->MFMA latencies and store bursts of the 1-wave/SIMD variants
// (r10/r11/r12 all ~223 µs, pacing experiments null) interleave across waves.
#define NT 8
__global__ __launch_bounds__(512, 2) void fused_kernel(
    const float* __restrict__ x, const float* __restrict__ y,
    const float* __restrict__ b, const unsigned short* __restrict__ wfrag,
    float* __restrict__ out) {
  __shared__ unsigned short wlds[65536];  // 128 KB: 4 weights x 4 kt x 8 ct x 1KB frag blocks
  {
    const float4* s = (const float4*)wfrag;
    float4* d = (float4*)wlds;
    const int t = threadIdx.x;
#pragma unroll
    for (int i = 0; i < 16; ++i) d[t + i * 512] = s[t + i * 512];
  }
  __syncthreads();

  const int wid = threadIdx.x >> 6;   // 0..7
  const int lane = threadIdx.x & 63;
  const int g = lane >> 4, li = lane & 15;
  const int lofs = lane * 8;  // ushort offset of this lane's 16B frag slice

  float breg[8];
#pragma unroll
  for (int ct = 0; ct < 8; ++ct) breg[ct] = b[ct * 16 + li];

  const int rowBase = blockIdx.x * 1024 + wid * 16;  // 8 waves x 16 rows x 8 iters
  const int rA0 = rowBase + li;

  // Distance-1 pipeline: ONE chunk buffer in flight.
  Chunk C;
  load_chunk(C, x, rA0, 0, g);
  float4 yAc = *(const float4*)(y + (size_t)rA0 * 4);

  // t-loop NOT unrolled (unrolling duplicates live ranges -> spills).
#pragma unroll 1
  for (int t = 0; t < NT; ++t) {
    const int R0 = rowBase + t * 128;   // 8 waves x 16 rows stride
    const int rowA = R0 + li;
    const int rowN = rowA + 128;

    // yE for THIS iter's epilogue: issued at build start, consumed per-ct
    // in the epilogue; y is 4 MB, L2-resident.
    float4 yE[4];
#pragma unroll
    for (int rr = 0; rr < 4; ++rr)
      yE[rr] = *(const float4*)(y + (size_t)(R0 + g * 4 + rr) * 4);

    // ---- build phase ----
    FragK FA[4];  // fully-unrolled compile-time indexing only
    convert_chunk(FA[0], C, yAc);        // (t,kt0): prefetched last iter
    load_chunk(C, x, rowA, 1, g);
    convert_chunk(FA[1], C, yAc);
    load_chunk(C, x, rowA, 2, g);
    convert_chunk(FA[2], C, yAc);
    load_chunk(C, x, rowA, 3, g);
    convert_chunk(FA[3], C, yAc);
    float4 yAn;
    if (t < NT - 1) {
      load_chunk(C, x, rowN, 0, g);      // (t+1,kt0): rides under MFMA phase
      yAn = *(const float4*)(y + (size_t)rowN * 4);
    }

    // ---- MFMA + store phase: stream ct with a 20-reg accumulator ----
#pragma unroll
    for (int ct = 0; ct < 8; ++ct) {
      // bias folded into accS init (MFMA C-in accumulates)
      f32x4 aS = {breg[ct], breg[ct], breg[ct], breg[ct]};
      const f32x4 zz = {0.f, 0.f, 0.f, 0.f};
      f32x4 aP = zz, aQ0 = zz, aQ1 = zz, aQ2 = zz;

#pragma unroll
      for (int kt = 0; kt < 4; ++kt) {
        const bf16x8 Bss = *(const bf16x8*)&wlds[((0 * 4 + kt) * 8 + ct) * 512 + lofs];
        const bf16x8 Bsv = *(const bf16x8*)&wlds[((1 * 4 + kt) * 8 + ct) * 512 + lofs];
        const bf16x8 Bvs = *(const bf16x8*)&wlds[((2 * 4 + kt) * 8 + ct) * 512 + lofs];
        const bf16x8 Bvv = *(const bf16x8*)&wlds[((3 * 4 + kt) * 8 + ct) * 512 + lofs];
        aS  = __builtin_amdgcn_mfma_f32_16x16x32_bf16(FA[kt].ss, Bss, aS,  0, 0, 0);
        aS  = __builtin_amdgcn_mfma_f32_16x16x32_bf16(FA[kt].dd, Bvv, aS,  0, 0, 0);
        aP  = __builtin_amdgcn_mfma_f32_16x16x32_bf16(FA[kt].sv, Bsv, aP,  0, 0, 0);
        aQ0 = __builtin_amdgcn_mfma_f32_16x16x32_bf16(FA[kt].v0, Bvs, aQ0, 0, 0, 0);
        aQ1 = __builtin_amdgcn_mfma_f32_16x16x32_bf16(FA[kt].v1, Bvs, aQ1, 0, 0, 0);
        aQ2 = __builtin_amdgcn_mfma_f32_16x16x32_bf16(FA[kt].v2, Bvs, aQ2, 0, 0, 0);
      }

      // per-ct epilogue: C/D layout col = lane&15, row = (lane>>4)*4 + reg
      // [m89-verified].  out_v row scaling by yv applied HERE (P/Q form).
      // Stores line-complete across adjacent ct phases.
#pragma unroll
      for (int rr = 0; rr < 4; ++rr) {
        const int row = R0 + g * 4 + rr;
        float* po = out + (size_t)row * 512;
        po[ct * 16 + li] = aS[rr];
        const float p = aP[rr];
        const int w = ct * 16 + li;
        float3 o;
        o.x = fmaf(yE[rr].y, p, aQ0[rr]);
        o.y = fmaf(yE[rr].z, p, aQ1[rr]);
        o.z = fmaf(yE[rr].w, p, aQ2[rr]);
        *(float3*)(po + 128 + 3 * w) = o;  // 12B contiguous per lane -> dwordx3
      }
    }

    if (t < NT - 1) yAc = yAn;
  }
}

extern "C" void kernel_launch(void* const* d_in, const int* in_sizes, int n_in,
                              void* d_out, int out_size, void* d_ws, size_t ws_size,
                              hipStream_t stream) {
  const float* x = (const float*)d_in[0];
  const float* y = (const float*)d_in[1];
  const float* wss = (const float*)d_in[2];
  const float* wsv = (const float*)d_in[3];
  const float* wvs = (const float*)d_in[4];
  const float* wvv = (const float*)d_in[5];
  const float* b = (const float*)d_in[6];
  float* out = (float*)d_out;
  unsigned short* wfrag = (unsigned short*)d_ws;  // 128 KB used

  wprep_kernel<<<256, 256, 0, stream>>>(wss, wsv, wvs, wvv, wfrag);
  fused_kernel<<<256, 512, 0, stream>>>(x, y, b, wfrag, out);
}

// Round 14
// 226.598 us; speedup vs baseline: 1.2607x; 1.2607x over previous
//
#include <hip/hip_runtime.h>

typedef __bf16 bf16x8 __attribute__((ext_vector_type(8)));
typedef float f32x4 __attribute__((ext_vector_type(4)));

#define INV_SQRT3f 0.57735026918962576f

// ---------------- kernel 0: weight prep into MFMA B-fragment layout ----------------
// For each weight W[c][w] (c = contraction, w = out col), place bf16 value at
// fragment slot: block (Wi,kt,ct) of 1KB, lane = (c&31)/8*16 + (w&15), j = c&7.
__global__ void wprep_kernel(const float* __restrict__ wss,
                             const float* __restrict__ wsv,
                             const float* __restrict__ wvs,
                             const float* __restrict__ wvv,
                             unsigned short* __restrict__ wfrag) {
  int tid = blockIdx.x * 256 + threadIdx.x;  // 0..65535
  int Wi = tid >> 14;
  int idx = tid & 16383;
  int c = idx >> 7;
  int w = idx & 127;
  const float* src = (Wi == 0) ? wss : (Wi == 1) ? wsv : (Wi == 2) ? wvs : wvv;
  float v = src[idx];
  if (Wi == 3) v *= INV_SQRT3f;  // fold inv_sqrt3 into w_vv
  unsigned u = __builtin_bit_cast(unsigned, v);
  u += 0x7FFFu + ((u >> 16) & 1u);  // RNE to bf16
  int kt = c >> 5, kk = c & 31, g = kk >> 3, j = kk & 7;
  int ct = w >> 4, n = w & 15;
  wfrag[(((Wi * 4 + kt) * 8 + ct) << 9) + (g * 16 + n) * 8 + j] = (unsigned short)(u >> 16);
}

// compile-time component select (indices constant after full unroll)
__device__ __forceinline__ float fc(const float4& v, int i) {
  return (i == 0) ? v.x : (i == 1) ? v.y : (i == 2) ? v.z : v.w;
}

// One kt-slice of a row's raw x data: 32 floats/lane (8 xs + 24 xv).
struct Chunk {
  float4 fs[2];
  float4 fv[6];
};

__device__ __forceinline__ void load_chunk(Chunk& c, const float* __restrict__ x,
                                           int rowA, int kt, int g) {
  const float* px = x + (size_t)rowA * 512;
#pragma unroll
  for (int q = 0; q < 2; ++q)
    c.fs[q] = *(const float4*)(px + kt * 32 + g * 8 + q * 4);
#pragma unroll
  for (int q = 0; q < 6; ++q)
    c.fv[q] = *(const float4*)(px + 128 + kt * 96 + g * 24 + q * 4);
}

// Fragments for one kt-slice: 6 per kt (yv applied at the OUTPUT in the
// epilogue — row-scaling commutes through the matmul; r10-verified).
struct FragK {
  bf16x8 ss, sv, dd, v0, v1, v2;
};

__device__ __forceinline__ void convert_chunk(FragK& F, const Chunk& c, const float4 yA) {
  const float ys = yA.x, yv0 = yA.y, yv1 = yA.z, yv2 = yA.w;
#pragma unroll
  for (int j = 0; j < 8; ++j) {
    float s = fc(c.fs[j >> 2], j & 3);
    float a = fc(c.fv[(3 * j) >> 2], (3 * j) & 3);
    float bb = fc(c.fv[(3 * j + 1) >> 2], (3 * j + 1) & 3);
    float cc = fc(c.fv[(3 * j + 2) >> 2], (3 * j + 2) & 3);
    F.ss[j] = (__bf16)(ys * s);
    F.sv[j] = (__bf16)(s);
    F.v0[j] = (__bf16)(ys * a);
    F.v1[j] = (__bf16)(ys * bb);
    F.v2[j] = (__bf16)(ys * cc);
    F.dd[j] = (__bf16)fmaf(a, yv0, fmaf(bb, yv1, cc * yv2));
  }
}

// r11 skeleton (PASSING, 222.7 µs = best), ONE structural change: FOUR chunk
// buffers, with ALL of iter t+1's x-loads issued inside iter t's MFMA phase
// (ct = 0/2/4/6).  The build phase becomes load-free.  Rationale: under
// BW-limited delivery a wave's 16 KB of build-phase loads (kt2/kt3 in
// r10/r11/r12 alike) take ~6K cycles to arrive at fair share -> the build
// stalls that long, and HBM then idles during the following MFMA phase.
// This was the shared constant of all three ~223 µs variants; moving the
// loads into the covered window is the only untested placement.
// Registers: FA 96 + C 128 + acc 20 + yE/misc ~50 ≈ 295 unified — fits the
// 512/wave budget at bounds(256,1) via AGPR overflow (proven r8-r12 regime;
// 2-waves/SIMD capping is closed: r9=288, r13=285, both cap-degraded).
#define NT 16
__global__ __launch_bounds__(256, 1) void fused_kernel(
    const float* __restrict__ x, const float* __restrict__ y,
    const float* __restrict__ b, const unsigned short* __restrict__ wfrag,
    float* __restrict__ out) {
  __shared__ unsigned short wlds[65536];  // 128 KB: 4 weights x 4 kt x 8 ct x 1KB frag blocks
  {
    const float4* s = (const float4*)wfrag;
    float4* d = (float4*)wlds;
    const int t = threadIdx.x;
#pragma unroll
    for (int i = 0; i < 32; ++i) d[t + i * 256] = s[t + i * 256];
  }
  __syncthreads();

  const int wid = threadIdx.x >> 6;
  const int lane = threadIdx.x & 63;
  const int g = lane >> 4, li = lane & 15;
  const int lofs = lane * 8;  // ushort offset of this lane's 16B frag slice

  float breg[8];
#pragma unroll
  for (int ct = 0; ct < 8; ++ct) breg[ct] = b[ct * 16 + li];

  const int rowBase = blockIdx.x * 1024 + wid * 16;  // 4 waves x 16 rows x 16 iters
  const int rA0 = rowBase + li;

  // Prologue: ALL FOUR kt-chunks of iter 0 in flight.
  Chunk C0, C1, C2, C3;
  load_chunk(C0, x, rA0, 0, g);
  load_chunk(C1, x, rA0, 1, g);
  load_chunk(C2, x, rA0, 2, g);
  load_chunk(C3, x, rA0, 3, g);
  float4 yAc = *(const float4*)(y + (size_t)rA0 * 4);

  // t-loop NOT unrolled (unrolling duplicates live ranges -> spills).
#pragma unroll 1
  for (int t = 0; t < NT; ++t) {
    const int R0 = rowBase + t * 64;
    const int rowN = R0 + 64 + li;

    // yE for THIS iter's epilogue: L2-resident y, covered by the converts.
    float4 yE[4];
#pragma unroll
    for (int rr = 0; rr < 4; ++rr)
      yE[rr] = *(const float4*)(y + (size_t)(R0 + g * 4 + rr) * 4);

    // ---- build phase: LOAD-FREE (all chunks prefetched last iter) ----
    FragK FA[4];  // fully-unrolled compile-time indexing only
    convert_chunk(FA[0], C0, yAc);
    convert_chunk(FA[1], C1, yAc);
    convert_chunk(FA[2], C2, yAc);
    convert_chunk(FA[3], C3, yAc);

    float4 yAn;

    // ---- MFMA + store phase: stream ct; issue t+1's loads at ct=0/2/4/6 ----
#pragma unroll
    for (int ct = 0; ct < 8; ++ct) {
      if (t < NT - 1) {
        if (ct == 0) load_chunk(C0, x, rowN, 0, g);
        if (ct == 2) load_chunk(C1, x, rowN, 1, g);
        if (ct == 4) load_chunk(C2, x, rowN, 2, g);
        if (ct == 6) {
          load_chunk(C3, x, rowN, 3, g);
          yAn = *(const float4*)(y + (size_t)rowN * 4);
        }
      }

      // bias folded into accS init (MFMA C-in accumulates)
      f32x4 aS = {breg[ct], breg[ct], breg[ct], breg[ct]};
      const f32x4 zz = {0.f, 0.f, 0.f, 0.f};
      f32x4 aP = zz, aQ0 = zz, aQ1 = zz, aQ2 = zz;

#pragma unroll
      for (int kt = 0; kt < 4; ++kt) {
        const bf16x8 Bss = *(const bf16x8*)&wlds[((0 * 4 + kt) * 8 + ct) * 512 + lofs];
        const bf16x8 Bsv = *(const bf16x8*)&wlds[((1 * 4 + kt) * 8 + ct) * 512 + lofs];
        const bf16x8 Bvs = *(const bf16x8*)&wlds[((2 * 4 + kt) * 8 + ct) * 512 + lofs];
        const bf16x8 Bvv = *(const bf16x8*)&wlds[((3 * 4 + kt) * 8 + ct) * 512 + lofs];
        aS  = __builtin_amdgcn_mfma_f32_16x16x32_bf16(FA[kt].ss, Bss, aS,  0, 0, 0);
        aS  = __builtin_amdgcn_mfma_f32_16x16x32_bf16(FA[kt].dd, Bvv, aS,  0, 0, 0);
        aP  = __builtin_amdgcn_mfma_f32_16x16x32_bf16(FA[kt].sv, Bsv, aP,  0, 0, 0);
        aQ0 = __builtin_amdgcn_mfma_f32_16x16x32_bf16(FA[kt].v0, Bvs, aQ0, 0, 0, 0);
        aQ1 = __builtin_amdgcn_mfma_f32_16x16x32_bf16(FA[kt].v1, Bvs, aQ1, 0, 0, 0);
        aQ2 = __builtin_amdgcn_mfma_f32_16x16x32_bf16(FA[kt].v2, Bvs, aQ2, 0, 0, 0);
      }

      // per-ct epilogue: C/D layout col = lane&15, row = (lane>>4)*4 + reg
      // [m89-verified].  out_v row scaling by yv applied HERE (P/Q form).
      // Stores line-complete across adjacent ct phases.
#pragma unroll
      for (int rr = 0; rr < 4; ++rr) {
        const int row = R0 + g * 4 + rr;
        float* po = out + (size_t)row * 512;
        po[ct * 16 + li] = aS[rr];
        const float p = aP[rr];
        const int w = ct * 16 + li;
        float3 o;
        o.x = fmaf(yE[rr].y, p, aQ0[rr]);
        o.y = fmaf(yE[rr].z, p, aQ1[rr]);
        o.z = fmaf(yE[rr].w, p, aQ2[rr]);
        *(float3*)(po + 128 + 3 * w) = o;  // 12B contiguous per lane -> dwordx3
      }
    }

    if (t < NT - 1) yAc = yAn;
  }
}

extern "C" void kernel_launch(void* const* d_in, const int* in_sizes, int n_in,
                              void* d_out, int out_size, void* d_ws, size_t ws_size,
                              hipStream_t stream) {
  const float* x = (const float*)d_in[0];
  const float* y = (const float*)d_in[1];
  const float* wss = (const float*)d_in[2];
  const float* wsv = (const float*)d_in[3];
  const float* wvs = (const float*)d_in[4];
  const float* wvv = (const float*)d_in[5];
  const float* b = (const float*)d_in[6];
  float* out = (float*)d_out;
  unsigned short* wfrag = (unsigned short*)d_ws;  // 128 KB used

  wprep_kernel<<<256, 256, 0, stream>>>(wss, wsv, wvs, wvv, wfrag);
  fused_kernel<<<256, 256, 0, stream>>>(x, y, b, wfrag, out);
}

// Round 15
// 222.453 us; speedup vs baseline: 1.2842x; 1.0186x over previous
//
#include <hip/hip_runtime.h>

typedef __bf16 bf16x8 __attribute__((ext_vector_type(8)));
typedef float f32x4 __attribute__((ext_vector_type(4)));

#define INV_SQRT3f 0.57735026918962576f

// ---------------- kernel 0: weight prep into MFMA B-fragment layout ----------------
// For each weight W[c][w] (c = contraction, w = out col), place bf16 value at
// fragment slot: block (Wi,kt,ct) of 1KB, lane = (c&31)/8*16 + (w&15), j = c&7.
__global__ void wprep_kernel(const float* __restrict__ wss,
                             const float* __restrict__ wsv,
                             const float* __restrict__ wvs,
                             const float* __restrict__ wvv,
                             unsigned short* __restrict__ wfrag) {
  int tid = blockIdx.x * 256 + threadIdx.x;  // 0..65535
  int Wi = tid >> 14;
  int idx = tid & 16383;
  int c = idx >> 7;
  int w = idx & 127;
  const float* src = (Wi == 0) ? wss : (Wi == 1) ? wsv : (Wi == 2) ? wvs : wvv;
  float v = src[idx];
  if (Wi == 3) v *= INV_SQRT3f;  // fold inv_sqrt3 into w_vv
  unsigned u = __builtin_bit_cast(unsigned, v);
  u += 0x7FFFu + ((u >> 16) & 1u);  // RNE to bf16
  int kt = c >> 5, kk = c & 31, g = kk >> 3, j = kk & 7;
  int ct = w >> 4, n = w & 15;
  wfrag[(((Wi * 4 + kt) * 8 + ct) << 9) + (g * 16 + n) * 8 + j] = (unsigned short)(u >> 16);
}

// compile-time component select (indices constant after full unroll)
__device__ __forceinline__ float fc(const float4& v, int i) {
  return (i == 0) ? v.x : (i == 1) ? v.y : (i == 2) ? v.z : v.w;
}

// One kt-slice of a row's raw x data: 32 floats/lane (8 xs + 24 xv).
struct Chunk {
  float4 fs[2];
  float4 fv[6];
};

__device__ __forceinline__ void load_chunk(Chunk& c, const float* __restrict__ x,
                                           int rowA, int kt, int g) {
  const float* px = x + (size_t)rowA * 512;
#pragma unroll
  for (int q = 0; q < 2; ++q)
    c.fs[q] = *(const float4*)(px + kt * 32 + g * 8 + q * 4);
#pragma unroll
  for (int q = 0; q < 6; ++q)
    c.fv[q] = *(const float4*)(px + 128 + kt * 96 + g * 24 + q * 4);
}

// Fragments for one kt-slice: 6 per kt (yv applied at the OUTPUT in the
// epilogue — row-scaling commutes through the matmul; r10-verified).
struct FragK {
  bf16x8 ss, sv, dd, v0, v1, v2;
};

__device__ __forceinline__ void convert_chunk(FragK& F, const Chunk& c, const float4 yA) {
  const float ys = yA.x, yv0 = yA.y, yv1 = yA.z, yv2 = yA.w;
#pragma unroll
  for (int j = 0; j < 8; ++j) {
    float s = fc(c.fs[j >> 2], j & 3);
    float a = fc(c.fv[(3 * j) >> 2], (3 * j) & 3);
    float bb = fc(c.fv[(3 * j + 1) >> 2], (3 * j + 1) & 3);
    float cc = fc(c.fv[(3 * j + 2) >> 2], (3 * j + 2) & 3);
    F.ss[j] = (__bf16)(ys * s);
    F.sv[j] = (__bf16)(s);
    F.v0[j] = (__bf16)(ys * a);
    F.v1[j] = (__bf16)(ys * bb);
    F.v2[j] = (__bf16)(ys * cc);
    F.dd[j] = (__bf16)fmaf(a, yv0, fmaf(bb, yv1, cc * yv2));
  }
}

// FINAL: byte-equivalent restore of the round-11 kernel — the best measured
// configuration (222.7 µs; ~4.7 TB/s effective on 1.05 GB ideal traffic,
// ~85-90% of the practical mixed-read/write HBM ceiling at 1 wave/SIMD).
// Exploration summary:
//  - load placement (dist-1 / dist-2 / staggered / fully-covered): all ±2%
//  - 2 waves/SIMD: requires <=256 unified regs; this structure needs ~295;
//    cap-forced variants degrade ~30% (r9/r13) or corrupt (r4/r5)
//  - leaner structures (acc-resident r7, 8-frag r8): 517 / 247.6 µs
//  - traffic: ideal (1.049 GB, r13 PMC); stores line-complete; LDS conflict-free
#define NT 16
__global__ __launch_bounds__(256, 1) void fused_kernel(
    const float* __restrict__ x, const float* __restrict__ y,
    const float* __restrict__ b, const unsigned short* __restrict__ wfrag,
    float* __restrict__ out) {
  __shared__ unsigned short wlds[65536];  // 128 KB: 4 weights x 4 kt x 8 ct x 1KB frag blocks
  {
    const float4* s = (const float4*)wfrag;
    float4* d = (float4*)wlds;
    const int t = threadIdx.x;
#pragma unroll
    for (int i = 0; i < 32; ++i) d[t + i * 256] = s[t + i * 256];
  }
  __syncthreads();

  const int wid = threadIdx.x >> 6;
  const int lane = threadIdx.x & 63;
  const int g = lane >> 4, li = lane & 15;
  const int lofs = lane * 8;  // ushort offset of this lane's 16B frag slice

  float breg[8];
#pragma unroll
  for (int ct = 0; ct < 8; ++ct) breg[ct] = b[ct * 16 + li];

  const int rowBase = blockIdx.x * 1024 + wid * 16;  // 4 waves x 16 rows x 16 iters
  const int rA0 = rowBase + li;

  // Distance-2 pipeline prologue: kt0 and kt1 of iter 0 in flight.
  Chunk C0, C1;
  load_chunk(C0, x, rA0, 0, g);
  load_chunk(C1, x, rA0, 1, g);
  float4 yAc = *(const float4*)(y + (size_t)rA0 * 4);

  // t-loop NOT unrolled (unrolling duplicates live ranges -> spills).
#pragma unroll 1
  for (int t = 0; t < NT; ++t) {
    const int R0 = rowBase + t * 64;
    const int rowA = R0 + li;
    const int rowN = rowA + 64;

    // yE for THIS iter's epilogue: issued at build start, consumed after the
    // whole MFMA phase -> latency fully hidden; y is 4 MB, L2-resident.
    float4 yE[4];
#pragma unroll
    for (int rr = 0; rr < 4; ++rr)
      yE[rr] = *(const float4*)(y + (size_t)(R0 + g * 4 + rr) * 4);

    // ---- build phase ----
    FragK FA[4];  // fully-unrolled compile-time indexing only
    convert_chunk(FA[0], C0, yAc);         // (t,kt0): loaded during prev MFMA -> hidden
    load_chunk(C0, x, rowA, 2, g);         // issue (t,kt2)
    convert_chunk(FA[1], C1, yAc);         // (t,kt1): loaded during prev MFMA -> hidden
    load_chunk(C1, x, rowA, 3, g);         // issue (t,kt3)
    convert_chunk(FA[2], C0, yAc);         // (t,kt2): ~1 convert of cover
    convert_chunk(FA[3], C1, yAc);         // (t,kt3): ~2 converts of cover

    // deep prefetch: (t+1)'s kt0/kt1 + yA ride under the entire MFMA phase
    float4 yAn;
    if (t < NT - 1) {
      load_chunk(C0, x, rowN, 0, g);
      load_chunk(C1, x, rowN, 1, g);
      yAn = *(const float4*)(y + (size_t)rowN * 4);
    }

    // ---- MFMA + store phase: stream ct with a 20-reg accumulator ----
#pragma unroll
    for (int ct = 0; ct < 8; ++ct) {
      // bias folded into accS init (MFMA C-in accumulates)
      f32x4 aS = {breg[ct], breg[ct], breg[ct], breg[ct]};
      const f32x4 zz = {0.f, 0.f, 0.f, 0.f};
      f32x4 aP = zz, aQ0 = zz, aQ1 = zz, aQ2 = zz;

#pragma unroll
      for (int kt = 0; kt < 4; ++kt) {
        const bf16x8 Bss = *(const bf16x8*)&wlds[((0 * 4 + kt) * 8 + ct) * 512 + lofs];
        const bf16x8 Bsv = *(const bf16x8*)&wlds[((1 * 4 + kt) * 8 + ct) * 512 + lofs];
        const bf16x8 Bvs = *(const bf16x8*)&wlds[((2 * 4 + kt) * 8 + ct) * 512 + lofs];
        const bf16x8 Bvv = *(const bf16x8*)&wlds[((3 * 4 + kt) * 8 + ct) * 512 + lofs];
        aS  = __builtin_amdgcn_mfma_f32_16x16x32_bf16(FA[kt].ss, Bss, aS,  0, 0, 0);
        aS  = __builtin_amdgcn_mfma_f32_16x16x32_bf16(FA[kt].dd, Bvv, aS,  0, 0, 0);
        aP  = __builtin_amdgcn_mfma_f32_16x16x32_bf16(FA[kt].sv, Bsv, aP,  0, 0, 0);
        aQ0 = __builtin_amdgcn_mfma_f32_16x16x32_bf16(FA[kt].v0, Bvs, aQ0, 0, 0, 0);
        aQ1 = __builtin_amdgcn_mfma_f32_16x16x32_bf16(FA[kt].v1, Bvs, aQ1, 0, 0, 0);
        aQ2 = __builtin_amdgcn_mfma_f32_16x16x32_bf16(FA[kt].v2, Bvs, aQ2, 0, 0, 0);
      }

      // per-ct epilogue: C/D layout col = lane&15, row = (lane>>4)*4 + reg
      // [m89-verified].  out_v row scaling by yv applied HERE (P/Q form).
      // Stores line-complete across adjacent ct phases.
#pragma unroll
      for (int rr = 0; rr < 4; ++rr) {
        const int row = R0 + g * 4 + rr;
        float* po = out + (size_t)row * 512;
        po[ct * 16 + li] = aS[rr];
        const float p = aP[rr];
        const int w = ct * 16 + li;
        float3 o;
        o.x = fmaf(yE[rr].y, p, aQ0[rr]);
        o.y = fmaf(yE[rr].z, p, aQ1[rr]);
        o.z = fmaf(yE[rr].w, p, aQ2[rr]);
        *(float3*)(po + 128 + 3 * w) = o;  // 12B contiguous per lane -> dwordx3
      }
    }

    if (t < NT - 1) yAc = yAn;
  }
}

extern "C" void kernel_launch(void* const* d_in, const int* in_sizes, int n_in,
                              void* d_out, int out_size, void* d_ws, size_t ws_size,
                              hipStream_t stream) {
  const float* x = (const float*)d_in[0];
  const float* y = (const float*)d_in[1];
  const float* wss = (const float*)d_in[2];
  const float* wsv = (const float*)d_in[3];
  const float* wvs = (const float*)d_in[4];
  const float* wvv = (const float*)d_in[5];
  const float* b = (const float*)d_in[6];
  float* out = (float*)d_out;
  unsigned short* wfrag = (unsigned short*)d_ws;  // 128 KB used

  wprep_kernel<<<256, 256, 0, stream>>>(wss, wsv, wvs, wvv, wfrag);
  fused_kernel<<<256, 256, 0, stream>>>(x, y, b, wfrag, out);
}